// Round 2
// baseline (11573.815 us; speedup 1.0000x reference)
//
#include <hip/hip_runtime.h>
#include <math.h>

#define D_ 2048
#define S_ 2048
#define DH_ 128
#define NH_ 16
#define F_ 5504
#define MTOK 4096

// ---------------- RMSNorm 1: f32 in -> f32 normed out ----------------
__global__ __launch_bounds__(256)
void k_rmsnorm1(const float* __restrict__ x, const float* __restrict__ w,
                float* __restrict__ out) {
  const int t = blockIdx.x, tid = threadIdx.x;
  const size_t off = (size_t)t * D_ + tid * 8;
  float4 x0 = *(const float4*)(x + off);
  float4 x1 = *(const float4*)(x + off + 4);
  float v[8] = {x0.x, x0.y, x0.z, x0.w, x1.x, x1.y, x1.z, x1.w};
  float ss = 0.f;
  #pragma unroll
  for (int i = 0; i < 8; ++i) ss += v[i] * v[i];
  #pragma unroll
  for (int o = 32; o > 0; o >>= 1) ss += __shfl_xor(ss, o, 64);
  __shared__ float red[4];
  if ((tid & 63) == 0) red[tid >> 6] = ss;
  __syncthreads();
  const float tot = red[0] + red[1] + red[2] + red[3];
  const float rstd = 1.0f / sqrtf(tot / (float)D_ + 1e-6f);
  float4 w0 = *(const float4*)(w + tid * 8);
  float4 w1 = *(const float4*)(w + tid * 8 + 4);
  float wv[8] = {w0.x, w0.y, w0.z, w0.w, w1.x, w1.y, w1.z, w1.w};
  float o0[8];
  #pragma unroll
  for (int i = 0; i < 8; ++i) o0[i] = v[i] * rstd * wv[i];
  *(float4*)(out + off)     = make_float4(o0[0], o0[1], o0[2], o0[3]);
  *(float4*)(out + off + 4) = make_float4(o0[4], o0[5], o0[6], o0[7]);
}

// ---------------- RMSNorm 2 + router (fp32 logits, exact argmax) ------
__global__ __launch_bounds__(256)
void k_rmsnorm2_router(const float* __restrict__ xin, const float* __restrict__ w,
                       const float* __restrict__ rw, const float* __restrict__ rb,
                       float* __restrict__ h2, int* __restrict__ choice) {
  const int t = blockIdx.x, tid = threadIdx.x;
  const size_t off = (size_t)t * D_ + tid * 8;
  float4 x0 = *(const float4*)(xin + off);
  float4 x1 = *(const float4*)(xin + off + 4);
  float v[8] = {x0.x, x0.y, x0.z, x0.w, x1.x, x1.y, x1.z, x1.w};
  float ss = 0.f;
  #pragma unroll
  for (int i = 0; i < 8; ++i) ss += v[i] * v[i];
  #pragma unroll
  for (int o = 32; o > 0; o >>= 1) ss += __shfl_xor(ss, o, 64);
  __shared__ float red[4];
  __shared__ float rl[8];
  if ((tid & 63) == 0) red[tid >> 6] = ss;
  __syncthreads();
  const float tot = red[0] + red[1] + red[2] + red[3];
  const float rstd = 1.0f / sqrtf(tot / (float)D_ + 1e-6f);
  float4 w0 = *(const float4*)(w + tid * 8);
  float4 w1 = *(const float4*)(w + tid * 8 + 4);
  float wv[8] = {w0.x, w0.y, w0.z, w0.w, w1.x, w1.y, w1.z, w1.w};
  float4 ra = *(const float4*)(rw + tid * 8);
  float4 rb4 = *(const float4*)(rw + tid * 8 + 4);
  float4 rc = *(const float4*)(rw + D_ + tid * 8);
  float4 rd = *(const float4*)(rw + D_ + tid * 8 + 4);
  float r0[8] = {ra.x, ra.y, ra.z, ra.w, rb4.x, rb4.y, rb4.z, rb4.w};
  float r1[8] = {rc.x, rc.y, rc.z, rc.w, rd.x, rd.y, rd.z, rd.w};
  float l0 = 0.f, l1 = 0.f;
  float ho[8];
  #pragma unroll
  for (int i = 0; i < 8; ++i) {
    const float h = v[i] * rstd * wv[i];
    ho[i] = h;
    l0 += h * r0[i];
    l1 += h * r1[i];
  }
  *(float4*)(h2 + off)     = make_float4(ho[0], ho[1], ho[2], ho[3]);
  *(float4*)(h2 + off + 4) = make_float4(ho[4], ho[5], ho[6], ho[7]);
  #pragma unroll
  for (int o = 32; o > 0; o >>= 1) {
    l0 += __shfl_xor(l0, o, 64);
    l1 += __shfl_xor(l1, o, 64);
  }
  if ((tid & 63) == 0) { rl[tid >> 6] = l0; rl[4 + (tid >> 6)] = l1; }
  __syncthreads();
  if (tid == 0) {
    const float L0 = rl[0] + rl[1] + rl[2] + rl[3] + rb[0];
    const float L1 = rl[4] + rl[5] + rl[6] + rl[7] + rb[1];
    choice[t] = (L1 > L0) ? 1 : 0;   // tie -> 0, matches np argmax-first
  }
}

// ---------------- RoPE (fp64 trig, in-place on fp32 Q and K) ----------
__global__ __launch_bounds__(256)
void k_rope(float* __restrict__ Q, float* __restrict__ K) {
  const int t = blockIdx.x;
  const int s = t & (S_ - 1);
  const int d = threadIdx.x & 63;
  const int hq = threadIdx.x >> 6;
  const double inv = pow(10000.0, -(double)d / 64.0);
  const double ang = (double)s * inv;
  const float cf = (float)cos(ang);
  const float sf = (float)sin(ang);
  #pragma unroll
  for (int i = 0; i < 4; ++i) {
    const int h = hq * 4 + i;
    const size_t idx = (size_t)t * D_ + h * DH_ + d;
    float x1 = Q[idx], x2 = Q[idx + 64];
    Q[idx]      = x1 * cf - x2 * sf;
    Q[idx + 64] = x2 * cf + x1 * sf;
    float y1 = K[idx], y2 = K[idx + 64];
    K[idx]      = y1 * cf - y2 * sf;
    K[idx + 64] = y2 * cf + y1 * sf;
  }
}

// ---------------- fp32 GEMM: C[M,N] = A[M,K] * W[N,K]^T (+epilogue) ----
// EPI 0: o = acc + bias[col]                      (QKV)
// EPI 1: o = acc + aux[idx]                       (wo + residual, aux=hidden)
// EPI 2: o = silu(acc)                            (gate)
// EPI 3: o = acc * aux[idx]                       (up; aux=g, C=g in-place)
// EPI 4: o = aux[idx] + (choice[row]==0 ? acc:0)  (down e1; aux=res2, C=out)
// EPI 5: o = C[idx]  + (choice[row]==1 ? acc:0)   (down e2; C=out RMW)
template<int EPI>
__global__ __launch_bounds__(256)
void k_gemm_f32(const float* __restrict__ A, const float* __restrict__ W,
                const float* __restrict__ bias, const float* aux,
                const int* __restrict__ choice, float* C, int N, int K) {
  __shared__ float As[16][132];
  __shared__ float Bs[16][140];   // skewed columns to break conflicts
  const int tid = threadIdx.x;
  const int m0 = blockIdx.y * 128, n0 = blockIdx.x * 128;
  const int tx = tid & 15, ty = tid >> 4;
  float acc[8][8];
  #pragma unroll
  for (int i = 0; i < 8; ++i)
    #pragma unroll
    for (int j = 0; j < 8; ++j) acc[i][j] = 0.f;

  const int srow = tid >> 1;
  const int skq = (tid & 1) * 8;
  const float* Ap = A + (size_t)(m0 + srow) * K + skq;
  const float* Wp = W + (size_t)(n0 + srow) * K + skq;
  const int sn = srow + ((srow >> 5) << 2);
  const int bn = tx * 8 + ((tx >> 2) << 2);

  for (int k0 = 0; k0 < K; k0 += 16) {
    float4 a0 = *(const float4*)(Ap + k0);
    float4 a1 = *(const float4*)(Ap + k0 + 4);
    float4 w0 = *(const float4*)(Wp + k0);
    float4 w1 = *(const float4*)(Wp + k0 + 4);
    As[skq + 0][srow] = a0.x; As[skq + 1][srow] = a0.y;
    As[skq + 2][srow] = a0.z; As[skq + 3][srow] = a0.w;
    As[skq + 4][srow] = a1.x; As[skq + 5][srow] = a1.y;
    As[skq + 6][srow] = a1.z; As[skq + 7][srow] = a1.w;
    Bs[skq + 0][sn] = w0.x; Bs[skq + 1][sn] = w0.y;
    Bs[skq + 2][sn] = w0.z; Bs[skq + 3][sn] = w0.w;
    Bs[skq + 4][sn] = w1.x; Bs[skq + 5][sn] = w1.y;
    Bs[skq + 6][sn] = w1.z; Bs[skq + 7][sn] = w1.w;
    __syncthreads();
    #pragma unroll
    for (int kk = 0; kk < 16; ++kk) {
      float a[8], b[8];
      *(float4*)&a[0] = *(const float4*)&As[kk][ty * 8];
      *(float4*)&a[4] = *(const float4*)&As[kk][ty * 8 + 4];
      *(float4*)&b[0] = *(const float4*)&Bs[kk][bn];
      *(float4*)&b[4] = *(const float4*)&Bs[kk][bn + 4];
      #pragma unroll
      for (int i = 0; i < 8; ++i)
        #pragma unroll
        for (int j = 0; j < 8; ++j)
          acc[i][j] = fmaf(a[i], b[j], acc[i][j]);
    }
    __syncthreads();
  }

  float bvals[8];
  if (EPI == 0) {
    float4 b0 = *(const float4*)(bias + n0 + tx * 8);
    float4 b1 = *(const float4*)(bias + n0 + tx * 8 + 4);
    bvals[0] = b0.x; bvals[1] = b0.y; bvals[2] = b0.z; bvals[3] = b0.w;
    bvals[4] = b1.x; bvals[5] = b1.y; bvals[6] = b1.z; bvals[7] = b1.w;
  }
  #pragma unroll
  for (int i = 0; i < 8; ++i) {
    const int r = m0 + ty * 8 + i;
    const size_t base = (size_t)r * N + n0 + tx * 8;
    float o[8];
    #pragma unroll
    for (int j = 0; j < 8; ++j) o[j] = acc[i][j];
    if (EPI == 0) {
      #pragma unroll
      for (int j = 0; j < 8; ++j) o[j] += bvals[j];
    } else if (EPI == 1) {
      float4 r0 = *(const float4*)(aux + base);
      float4 r1 = *(const float4*)(aux + base + 4);
      o[0] += r0.x; o[1] += r0.y; o[2] += r0.z; o[3] += r0.w;
      o[4] += r1.x; o[5] += r1.y; o[6] += r1.z; o[7] += r1.w;
    } else if (EPI == 2) {
      #pragma unroll
      for (int j = 0; j < 8; ++j) o[j] = o[j] / (1.0f + expf(-o[j]));
    } else if (EPI == 3) {
      float4 g0 = *(const float4*)(aux + base);
      float4 g1 = *(const float4*)(aux + base + 4);
      o[0] *= g0.x; o[1] *= g0.y; o[2] *= g0.z; o[3] *= g0.w;
      o[4] *= g1.x; o[5] *= g1.y; o[6] *= g1.z; o[7] *= g1.w;
    } else if (EPI == 4) {
      const float m = (choice[r] == 0) ? 1.0f : 0.0f;
      float4 r0 = *(const float4*)(aux + base);
      float4 r1 = *(const float4*)(aux + base + 4);
      o[0] = r0.x + m * o[0]; o[1] = r0.y + m * o[1];
      o[2] = r0.z + m * o[2]; o[3] = r0.w + m * o[3];
      o[4] = r1.x + m * o[4]; o[5] = r1.y + m * o[5];
      o[6] = r1.z + m * o[6]; o[7] = r1.w + m * o[7];
    } else {
      const float m = (choice[r] == 1) ? 1.0f : 0.0f;
      float4 r0 = *(const float4*)(C + base);
      float4 r1 = *(const float4*)(C + base + 4);
      o[0] = r0.x + m * o[0]; o[1] = r0.y + m * o[1];
      o[2] = r0.z + m * o[2]; o[3] = r0.w + m * o[3];
      o[4] = r1.x + m * o[4]; o[5] = r1.y + m * o[5];
      o[6] = r1.z + m * o[6]; o[7] = r1.w + m * o[7];
    }
    *(float4*)(C + base)     = make_float4(o[0], o[1], o[2], o[3]);
    *(float4*)(C + base + 4) = make_float4(o[4], o[5], o[6], o[7]);
  }
}

// ---------------- fp32 flash attention (causal) ------------------------
__global__ __launch_bounds__(256)
void k_attn(const float* __restrict__ Q, const float* __restrict__ K,
            const float* __restrict__ V, float* __restrict__ O) {
  __shared__ float Ks[32][144];
  __shared__ float Vs[32][144];
  const int qt = blockIdx.x, h = blockIdx.y, b = blockIdx.z;
  const int tid = threadIdx.x;
  const int ql = tid >> 2, c4 = tid & 3;
  const int qrow = qt * 64 + ql;
  const size_t rq = (size_t)(b * S_ + qrow);
  const float* qp = Q + rq * D_ + h * DH_ + c4 * 32;
  float4 q4[8], o4[8];
  #pragma unroll
  for (int i = 0; i < 8; ++i) {
    q4[i] = *(const float4*)(qp + i * 4);
    o4[i] = make_float4(0.f, 0.f, 0.f, 0.f);
  }
  float mrun = -INFINITY, lrun = 0.f;
  const float scale = 0.088388347648318447f;  // 1/sqrt(128)
  const int nkt = 2 * qt + 2;
  for (int jt = 0; jt < nkt; ++jt) {
    const int kv0 = jt * 32;
    #pragma unroll
    for (int u = 0; u < 4; ++u) {
      const int ci = u * 256 + tid;
      const int r = ci >> 5, lc = ci & 31;
      const int sc = (lc >> 3) * 36 + (lc & 7) * 4;
      const size_t g = (size_t)(b * S_ + kv0 + r) * D_ + h * DH_ + lc * 4;
      *(float4*)&Ks[r][sc] = *(const float4*)(K + g);
      *(float4*)&Vs[r][sc] = *(const float4*)(V + g);
    }
    __syncthreads();
    float s[32];
    #pragma unroll
    for (int kv = 0; kv < 32; ++kv) {
      float p = 0.f;
      #pragma unroll
      for (int d4 = 0; d4 < 8; ++d4) {
        float4 kk = *(const float4*)&Ks[kv][c4 * 36 + d4 * 4];
        p = fmaf(q4[d4].x, kk.x, p); p = fmaf(q4[d4].y, kk.y, p);
        p = fmaf(q4[d4].z, kk.z, p); p = fmaf(q4[d4].w, kk.w, p);
      }
      p += __shfl_xor(p, 1);
      p += __shfl_xor(p, 2);
      s[kv] = (kv0 + kv > qrow) ? -INFINITY : p * scale;
    }
    float mt = s[0];
    #pragma unroll
    for (int kv = 1; kv < 32; ++kv) mt = fmaxf(mt, s[kv]);
    const float mnew = fmaxf(mrun, mt);
    const float alpha = expf(mrun - mnew);
    float psum = 0.f;
    #pragma unroll
    for (int kv = 0; kv < 32; ++kv) { s[kv] = expf(s[kv] - mnew); psum += s[kv]; }
    lrun = lrun * alpha + psum;
    mrun = mnew;
    #pragma unroll
    for (int i = 0; i < 8; ++i) {
      o4[i].x *= alpha; o4[i].y *= alpha; o4[i].z *= alpha; o4[i].w *= alpha;
    }
    #pragma unroll
    for (int kv = 0; kv < 32; ++kv) {
      const float pv = s[kv];
      #pragma unroll
      for (int d4 = 0; d4 < 8; ++d4) {
        float4 vv = *(const float4*)&Vs[kv][c4 * 36 + d4 * 4];
        o4[d4].x = fmaf(pv, vv.x, o4[d4].x); o4[d4].y = fmaf(pv, vv.y, o4[d4].y);
        o4[d4].z = fmaf(pv, vv.z, o4[d4].z); o4[d4].w = fmaf(pv, vv.w, o4[d4].w);
      }
    }
    __syncthreads();
  }
  const float invl = 1.0f / lrun;
  float* op = O + rq * D_ + h * DH_ + c4 * 32;
  #pragma unroll
  for (int d4 = 0; d4 < 8; ++d4)
    *(float4*)(op + d4 * 4) = make_float4(o4[d4].x * invl, o4[d4].y * invl,
                                          o4[d4].z * invl, o4[d4].w * invl);
}

// ---------------- launcher --------------------------------------------
extern "C" void kernel_launch(void* const* d_in, const int* in_sizes, int n_in,
                              void* d_out, int out_size, void* d_ws, size_t ws_size,
                              hipStream_t stream) {
  (void)in_sizes; (void)n_in; (void)out_size; (void)ws_size;
  const float* hidden = (const float*)d_in[0];
  const float* ln1w   = (const float*)d_in[1];
  const float* wq     = (const float*)d_in[2];
  const float* bq     = (const float*)d_in[3];
  const float* wk     = (const float*)d_in[4];
  const float* bk     = (const float*)d_in[5];
  const float* wv     = (const float*)d_in[6];
  const float* bv     = (const float*)d_in[7];
  const float* wo     = (const float*)d_in[8];
  const float* ln2w   = (const float*)d_in[9];
  const float* e1g    = (const float*)d_in[10];
  const float* e1u    = (const float*)d_in[11];
  const float* e1d    = (const float*)d_in[12];
  const float* e2g    = (const float*)d_in[13];
  const float* e2u    = (const float*)d_in[14];
  const float* e2d    = (const float*)d_in[15];
  const float* rw     = (const float*)d_in[16];
  const float* rb     = (const float*)d_in[17];
  float* out = (float*)d_out;
  char* ws = (char*)d_ws;

  const size_t MB = 1024 * 1024;
  float* h1n  = (float*)(ws);              // [0,32M)  -> reused as ctx
  float* Qb   = (float*)(ws + 32 * MB);    // [32,64M) -> reused as res2
  float* Kb   = (float*)(ws + 64 * MB);    // [64,96M) -> reused as h2
  float* Vb   = (float*)(ws + 96 * MB);    // [96,128M)-> dead after attn
  float* ctx  = h1n;
  float* res2 = Qb;
  float* h2   = Kb;
  int*   chs  = (int*)(ws + 96 * MB);      // 16 KiB over dead Vb
  float* g    = (float*)(ws + 97 * MB);    // [97,183M) over dead Vb+beyond

  k_rmsnorm1<<<MTOK, 256, 0, stream>>>(hidden, ln1w, h1n);

  dim3 gQKV(D_ / 128, MTOK / 128);
  k_gemm_f32<0><<<gQKV, 256, 0, stream>>>(h1n, wq, bq, nullptr, nullptr, Qb, D_, D_);
  k_gemm_f32<0><<<gQKV, 256, 0, stream>>>(h1n, wk, bk, nullptr, nullptr, Kb, D_, D_);
  k_gemm_f32<0><<<gQKV, 256, 0, stream>>>(h1n, wv, bv, nullptr, nullptr, Vb, D_, D_);

  k_rope<<<MTOK, 256, 0, stream>>>(Qb, Kb);

  k_attn<<<dim3(S_ / 64, NH_, 2), 256, 0, stream>>>(Qb, Kb, Vb, ctx);

  k_gemm_f32<1><<<gQKV, 256, 0, stream>>>(ctx, wo, nullptr, hidden, nullptr, res2, D_, D_);

  k_rmsnorm2_router<<<MTOK, 256, 0, stream>>>(res2, ln2w, rw, rb, h2, chs);

  dim3 gFU(F_ / 128, MTOK / 128), gDN(D_ / 128, MTOK / 128);
  // expert 1
  k_gemm_f32<2><<<gFU, 256, 0, stream>>>(h2, e1g, nullptr, nullptr, nullptr, g, F_, D_);
  k_gemm_f32<3><<<gFU, 256, 0, stream>>>(h2, e1u, nullptr, g, nullptr, g, F_, D_);
  k_gemm_f32<4><<<gDN, 256, 0, stream>>>(g, e1d, nullptr, res2, chs, out, D_, F_);
  // expert 2
  k_gemm_f32<2><<<gFU, 256, 0, stream>>>(h2, e2g, nullptr, nullptr, nullptr, g, F_, D_);
  k_gemm_f32<3><<<gFU, 256, 0, stream>>>(h2, e2u, nullptr, g, nullptr, g, F_, D_);
  k_gemm_f32<5><<<gDN, 256, 0, stream>>>(g, e2d, nullptr, res2, chs, out, D_, F_);
}

// Round 3
// 5550.249 us; speedup vs baseline: 2.0853x; 2.0853x over previous
//
#include <hip/hip_runtime.h>
#include <math.h>

typedef unsigned short u16;
typedef unsigned int u32;

#define D_ 2048
#define S_ 2048
#define DH_ 128
#define NH_ 16
#define F_ 5504
#define MTOK 4096

typedef __bf16 bf16x8 __attribute__((ext_vector_type(8)));
typedef float f32x4 __attribute__((ext_vector_type(4)));

__device__ __forceinline__ float bf2f(u32 u) {
  union { u32 i; float f; } x; x.i = u << 16; return x.f;
}
__device__ __forceinline__ u16 f2bf(float f) {
  u32 x = __float_as_uint(f);
  return (u16)((x + 0x7fffu + ((x >> 16) & 1u)) >> 16);
}

// ---------------- fp32 -> bf16 elementwise convert (weights) ----------
__global__ __launch_bounds__(256)
void k_f2bf(const float* __restrict__ src, u16* __restrict__ dst) {
  const size_t i = ((size_t)blockIdx.x * 256 + threadIdx.x) * 8;
  float4 a = *(const float4*)(src + i);
  float4 b = *(const float4*)(src + i + 4);
  uint4 p;
  p.x = f2bf(a.x) | ((u32)f2bf(a.y) << 16);
  p.y = f2bf(a.z) | ((u32)f2bf(a.w) << 16);
  p.z = f2bf(b.x) | ((u32)f2bf(b.y) << 16);
  p.w = f2bf(b.z) | ((u32)f2bf(b.w) << 16);
  *(uint4*)(dst + i) = p;
}

// ---------------- RMSNorm 1: f32 in -> f32 normed out ----------------
__global__ __launch_bounds__(256)
void k_rmsnorm1(const float* __restrict__ x, const float* __restrict__ w,
                float* __restrict__ out) {
  const int t = blockIdx.x, tid = threadIdx.x;
  const size_t off = (size_t)t * D_ + tid * 8;
  float4 x0 = *(const float4*)(x + off);
  float4 x1 = *(const float4*)(x + off + 4);
  float v[8] = {x0.x, x0.y, x0.z, x0.w, x1.x, x1.y, x1.z, x1.w};
  float ss = 0.f;
  #pragma unroll
  for (int i = 0; i < 8; ++i) ss += v[i] * v[i];
  #pragma unroll
  for (int o = 32; o > 0; o >>= 1) ss += __shfl_xor(ss, o, 64);
  __shared__ float red[4];
  if ((tid & 63) == 0) red[tid >> 6] = ss;
  __syncthreads();
  const float tot = red[0] + red[1] + red[2] + red[3];
  const float rstd = 1.0f / sqrtf(tot / (float)D_ + 1e-6f);
  float4 w0 = *(const float4*)(w + tid * 8);
  float4 w1 = *(const float4*)(w + tid * 8 + 4);
  float wv[8] = {w0.x, w0.y, w0.z, w0.w, w1.x, w1.y, w1.z, w1.w};
  float o0[8];
  #pragma unroll
  for (int i = 0; i < 8; ++i) o0[i] = v[i] * rstd * wv[i];
  *(float4*)(out + off)     = make_float4(o0[0], o0[1], o0[2], o0[3]);
  *(float4*)(out + off + 4) = make_float4(o0[4], o0[5], o0[6], o0[7]);
}

// -------- RMSNorm 2 + router (fp32 logits, exact argmax; h2 -> bf16) --
__global__ __launch_bounds__(256)
void k_rmsnorm2_router(const float* __restrict__ xin, const float* __restrict__ w,
                       const float* __restrict__ rw, const float* __restrict__ rb,
                       u16* __restrict__ h2, int* __restrict__ choice) {
  const int t = blockIdx.x, tid = threadIdx.x;
  const size_t off = (size_t)t * D_ + tid * 8;
  float4 x0 = *(const float4*)(xin + off);
  float4 x1 = *(const float4*)(xin + off + 4);
  float v[8] = {x0.x, x0.y, x0.z, x0.w, x1.x, x1.y, x1.z, x1.w};
  float ss = 0.f;
  #pragma unroll
  for (int i = 0; i < 8; ++i) ss += v[i] * v[i];
  #pragma unroll
  for (int o = 32; o > 0; o >>= 1) ss += __shfl_xor(ss, o, 64);
  __shared__ float red[4];
  __shared__ float rl[8];
  if ((tid & 63) == 0) red[tid >> 6] = ss;
  __syncthreads();
  const float tot = red[0] + red[1] + red[2] + red[3];
  const float rstd = 1.0f / sqrtf(tot / (float)D_ + 1e-6f);
  float4 w0 = *(const float4*)(w + tid * 8);
  float4 w1 = *(const float4*)(w + tid * 8 + 4);
  float wv[8] = {w0.x, w0.y, w0.z, w0.w, w1.x, w1.y, w1.z, w1.w};
  float4 ra = *(const float4*)(rw + tid * 8);
  float4 rb4 = *(const float4*)(rw + tid * 8 + 4);
  float4 rc = *(const float4*)(rw + D_ + tid * 8);
  float4 rd = *(const float4*)(rw + D_ + tid * 8 + 4);
  float r0[8] = {ra.x, ra.y, ra.z, ra.w, rb4.x, rb4.y, rb4.z, rb4.w};
  float r1[8] = {rc.x, rc.y, rc.z, rc.w, rd.x, rd.y, rd.z, rd.w};
  float l0 = 0.f, l1 = 0.f;
  u32 hb[8];
  #pragma unroll
  for (int i = 0; i < 8; ++i) {
    const float h = v[i] * rstd * wv[i];
    hb[i] = f2bf(h);
    l0 += h * r0[i];
    l1 += h * r1[i];
  }
  uint4 up;
  up.x = hb[0] | (hb[1] << 16); up.y = hb[2] | (hb[3] << 16);
  up.z = hb[4] | (hb[5] << 16); up.w = hb[6] | (hb[7] << 16);
  *(uint4*)(h2 + off) = up;
  #pragma unroll
  for (int o = 32; o > 0; o >>= 1) {
    l0 += __shfl_xor(l0, o, 64);
    l1 += __shfl_xor(l1, o, 64);
  }
  if ((tid & 63) == 0) { rl[tid >> 6] = l0; rl[4 + (tid >> 6)] = l1; }
  __syncthreads();
  if (tid == 0) {
    const float L0 = rl[0] + rl[1] + rl[2] + rl[3] + rb[0];
    const float L1 = rl[4] + rl[5] + rl[6] + rl[7] + rb[1];
    choice[t] = (L1 > L0) ? 1 : 0;   // tie -> 0, matches np argmax-first
  }
}

// ---------------- RoPE (fp64 trig, in-place on fp32 Q and K) ----------
__global__ __launch_bounds__(256)
void k_rope(float* __restrict__ Q, float* __restrict__ K) {
  const int t = blockIdx.x;
  const int s = t & (S_ - 1);
  const int d = threadIdx.x & 63;
  const int hq = threadIdx.x >> 6;
  const double inv = pow(10000.0, -(double)d / 64.0);
  const double ang = (double)s * inv;
  const float cf = (float)cos(ang);
  const float sf = (float)sin(ang);
  #pragma unroll
  for (int i = 0; i < 4; ++i) {
    const int h = hq * 4 + i;
    const size_t idx = (size_t)t * D_ + h * DH_ + d;
    float x1 = Q[idx], x2 = Q[idx + 64];
    Q[idx]      = x1 * cf - x2 * sf;
    Q[idx + 64] = x2 * cf + x1 * sf;
    float y1 = K[idx], y2 = K[idx + 64];
    K[idx]      = y1 * cf - y2 * sf;
    K[idx + 64] = y2 * cf + y1 * sf;
  }
}

// ---------------- fp32 GEMM: C[M,N] = A[M,K] * W[N,K]^T (+epilogue) ----
// EPI 0: o = acc + bias[col]      (QKV)
// EPI 1: o = acc + aux[idx]       (wo + residual)
template<int EPI>
__global__ __launch_bounds__(256)
void k_gemm_f32(const float* __restrict__ A, const float* __restrict__ W,
                const float* __restrict__ bias, const float* aux,
                float* C, int N, int K) {
  __shared__ float As[16][132];
  __shared__ float Bs[16][140];
  const int tid = threadIdx.x;
  const int m0 = blockIdx.y * 128, n0 = blockIdx.x * 128;
  const int tx = tid & 15, ty = tid >> 4;
  float acc[8][8];
  #pragma unroll
  for (int i = 0; i < 8; ++i)
    #pragma unroll
    for (int j = 0; j < 8; ++j) acc[i][j] = 0.f;

  const int srow = tid >> 1;
  const int skq = (tid & 1) * 8;
  const float* Ap = A + (size_t)(m0 + srow) * K + skq;
  const float* Wp = W + (size_t)(n0 + srow) * K + skq;
  const int sn = srow + ((srow >> 5) << 2);
  const int bn = tx * 8 + ((tx >> 2) << 2);

  for (int k0 = 0; k0 < K; k0 += 16) {
    float4 a0 = *(const float4*)(Ap + k0);
    float4 a1 = *(const float4*)(Ap + k0 + 4);
    float4 w0 = *(const float4*)(Wp + k0);
    float4 w1 = *(const float4*)(Wp + k0 + 4);
    As[skq + 0][srow] = a0.x; As[skq + 1][srow] = a0.y;
    As[skq + 2][srow] = a0.z; As[skq + 3][srow] = a0.w;
    As[skq + 4][srow] = a1.x; As[skq + 5][srow] = a1.y;
    As[skq + 6][srow] = a1.z; As[skq + 7][srow] = a1.w;
    Bs[skq + 0][sn] = w0.x; Bs[skq + 1][sn] = w0.y;
    Bs[skq + 2][sn] = w0.z; Bs[skq + 3][sn] = w0.w;
    Bs[skq + 4][sn] = w1.x; Bs[skq + 5][sn] = w1.y;
    Bs[skq + 6][sn] = w1.z; Bs[skq + 7][sn] = w1.w;
    __syncthreads();
    #pragma unroll
    for (int kk = 0; kk < 16; ++kk) {
      float a[8], b[8];
      *(float4*)&a[0] = *(const float4*)&As[kk][ty * 8];
      *(float4*)&a[4] = *(const float4*)&As[kk][ty * 8 + 4];
      *(float4*)&b[0] = *(const float4*)&Bs[kk][bn];
      *(float4*)&b[4] = *(const float4*)&Bs[kk][bn + 4];
      #pragma unroll
      for (int i = 0; i < 8; ++i)
        #pragma unroll
        for (int j = 0; j < 8; ++j)
          acc[i][j] = fmaf(a[i], b[j], acc[i][j]);
    }
    __syncthreads();
  }

  float bvals[8];
  if (EPI == 0) {
    float4 b0 = *(const float4*)(bias + n0 + tx * 8);
    float4 b1 = *(const float4*)(bias + n0 + tx * 8 + 4);
    bvals[0] = b0.x; bvals[1] = b0.y; bvals[2] = b0.z; bvals[3] = b0.w;
    bvals[4] = b1.x; bvals[5] = b1.y; bvals[6] = b1.z; bvals[7] = b1.w;
  }
  #pragma unroll
  for (int i = 0; i < 8; ++i) {
    const int r = m0 + ty * 8 + i;
    const size_t base = (size_t)r * N + n0 + tx * 8;
    float o[8];
    #pragma unroll
    for (int j = 0; j < 8; ++j) o[j] = acc[i][j];
    if (EPI == 0) {
      #pragma unroll
      for (int j = 0; j < 8; ++j) o[j] += bvals[j];
    } else {
      float4 r0 = *(const float4*)(aux + base);
      float4 r1 = *(const float4*)(aux + base + 4);
      o[0] += r0.x; o[1] += r0.y; o[2] += r0.z; o[3] += r0.w;
      o[4] += r1.x; o[5] += r1.y; o[6] += r1.z; o[7] += r1.w;
    }
    *(float4*)(C + base)     = make_float4(o[0], o[1], o[2], o[3]);
    *(float4*)(C + base + 4) = make_float4(o[4], o[5], o[6], o[7]);
  }
}

// ---------------- fp32 flash attention (causal) ------------------------
__global__ __launch_bounds__(256)
void k_attn(const float* __restrict__ Q, const float* __restrict__ K,
            const float* __restrict__ V, float* __restrict__ O) {
  __shared__ float Ks[32][144];
  __shared__ float Vs[32][144];
  const int qt = blockIdx.x, h = blockIdx.y, b = blockIdx.z;
  const int tid = threadIdx.x;
  const int ql = tid >> 2, c4 = tid & 3;
  const int qrow = qt * 64 + ql;
  const size_t rq = (size_t)(b * S_ + qrow);
  const float* qp = Q + rq * D_ + h * DH_ + c4 * 32;
  float4 q4[8], o4[8];
  #pragma unroll
  for (int i = 0; i < 8; ++i) {
    q4[i] = *(const float4*)(qp + i * 4);
    o4[i] = make_float4(0.f, 0.f, 0.f, 0.f);
  }
  float mrun = -INFINITY, lrun = 0.f;
  const float scale = 0.088388347648318447f;
  const int nkt = 2 * qt + 2;
  for (int jt = 0; jt < nkt; ++jt) {
    const int kv0 = jt * 32;
    #pragma unroll
    for (int u = 0; u < 4; ++u) {
      const int ci = u * 256 + tid;
      const int r = ci >> 5, lc = ci & 31;
      const int sc = (lc >> 3) * 36 + (lc & 7) * 4;
      const size_t g = (size_t)(b * S_ + kv0 + r) * D_ + h * DH_ + lc * 4;
      *(float4*)&Ks[r][sc] = *(const float4*)(K + g);
      *(float4*)&Vs[r][sc] = *(const float4*)(V + g);
    }
    __syncthreads();
    float s[32];
    #pragma unroll
    for (int kv = 0; kv < 32; ++kv) {
      float p = 0.f;
      #pragma unroll
      for (int d4 = 0; d4 < 8; ++d4) {
        float4 kk = *(const float4*)&Ks[kv][c4 * 36 + d4 * 4];
        p = fmaf(q4[d4].x, kk.x, p); p = fmaf(q4[d4].y, kk.y, p);
        p = fmaf(q4[d4].z, kk.z, p); p = fmaf(q4[d4].w, kk.w, p);
      }
      p += __shfl_xor(p, 1);
      p += __shfl_xor(p, 2);
      s[kv] = (kv0 + kv > qrow) ? -INFINITY : p * scale;
    }
    float mt = s[0];
    #pragma unroll
    for (int kv = 1; kv < 32; ++kv) mt = fmaxf(mt, s[kv]);
    const float mnew = fmaxf(mrun, mt);
    const float alpha = expf(mrun - mnew);
    float psum = 0.f;
    #pragma unroll
    for (int kv = 0; kv < 32; ++kv) { s[kv] = expf(s[kv] - mnew); psum += s[kv]; }
    lrun = lrun * alpha + psum;
    mrun = mnew;
    #pragma unroll
    for (int i = 0; i < 8; ++i) {
      o4[i].x *= alpha; o4[i].y *= alpha; o4[i].z *= alpha; o4[i].w *= alpha;
    }
    #pragma unroll
    for (int kv = 0; kv < 32; ++kv) {
      const float pv = s[kv];
      #pragma unroll
      for (int d4 = 0; d4 < 8; ++d4) {
        float4 vv = *(const float4*)&Vs[kv][c4 * 36 + d4 * 4];
        o4[d4].x = fmaf(pv, vv.x, o4[d4].x); o4[d4].y = fmaf(pv, vv.y, o4[d4].y);
        o4[d4].z = fmaf(pv, vv.z, o4[d4].z); o4[d4].w = fmaf(pv, vv.w, o4[d4].w);
      }
    }
    __syncthreads();
  }
  const float invl = 1.0f / lrun;
  float* op = O + rq * D_ + h * DH_ + c4 * 32;
  #pragma unroll
  for (int d4 = 0; d4 < 8; ++d4)
    *(float4*)(op + d4 * 4) = make_float4(o4[d4].x * invl, o4[d4].y * invl,
                                          o4[d4].z * invl, o4[d4].w * invl);
}

// ------- bf16 MFMA GEMM (m97 structure): C = A[M,K] * W[N,K]^T ---------
// EPI 0: C(bf16)[idx] = silu(acc)                        (gate)
// EPI 1: C(bf16)[idx] = acc * gbuf[idx]                  (up, in-place ok)
// EPI 2: C(f32)[idx]  = resf[idx] + (choice==0 ? acc:0)  (down e1)
// EPI 3: C(f32)[idx] += (choice==1 ? acc:0)              (down e2, RMW)
template<int EPI>
__global__ __launch_bounds__(256)
void k_moe_bf16(const u16* __restrict__ A, const u16* __restrict__ W,
                const u16* __restrict__ gbuf, const float* __restrict__ resf,
                const int* __restrict__ choice, void* Cv, int N, int K) {
  __shared__ u16 As[128 * 32];
  __shared__ u16 Bs[128 * 32];
  const int tid = threadIdx.x;
  const int wave = tid >> 6, lane = tid & 63;
  const int quad = lane >> 4, l16 = lane & 15;
  const int m0 = blockIdx.y * 128, n0 = blockIdx.x * 128;
  const int wm = (wave >> 1) * 64, wn = (wave & 1) * 64;
  f32x4 acc[4][4];
  #pragma unroll
  for (int i = 0; i < 4; ++i)
    #pragma unroll
    for (int j = 0; j < 4; ++j) acc[i][j] = 0;

  for (int k0 = 0; k0 < K; k0 += 32) {
    #pragma unroll
    for (int c = 0; c < 2; ++c) {
      const int ci = (c * 4 + wave) * 64 + lane;
      const int row = ci >> 2, ko = (ci & 3) << 3;
      __builtin_amdgcn_global_load_lds(
          (const __attribute__((address_space(1))) void*)(A + (size_t)(m0 + row) * K + k0 + ko),
          (__attribute__((address_space(3))) void*)(As + (size_t)(c * 4 + wave) * 512),
          16, 0, 0);
      __builtin_amdgcn_global_load_lds(
          (const __attribute__((address_space(1))) void*)(W + (size_t)(n0 + row) * K + k0 + ko),
          (__attribute__((address_space(3))) void*)(Bs + (size_t)(c * 4 + wave) * 512),
          16, 0, 0);
    }
    __syncthreads();
    bf16x8 af[4], bfr[4];
    #pragma unroll
    for (int i = 0; i < 4; ++i)
      af[i] = *(const bf16x8*)(As + (wm + i * 16 + l16) * 32 + quad * 8);
    #pragma unroll
    for (int j = 0; j < 4; ++j)
      bfr[j] = *(const bf16x8*)(Bs + (wn + j * 16 + l16) * 32 + quad * 8);
    #pragma unroll
    for (int i = 0; i < 4; ++i)
      #pragma unroll
      for (int j = 0; j < 4; ++j)
        acc[i][j] = __builtin_amdgcn_mfma_f32_16x16x32_bf16(af[i], bfr[j], acc[i][j], 0, 0, 0);
    __syncthreads();
  }

  #pragma unroll
  for (int i = 0; i < 4; ++i) {
    #pragma unroll
    for (int r = 0; r < 4; ++r) {
      const int row = m0 + wm + i * 16 + quad * 4 + r;
      #pragma unroll
      for (int j = 0; j < 4; ++j) {
        const int col = n0 + wn + j * 16 + l16;
        const float v = acc[i][j][r];
        const size_t idx = (size_t)row * N + col;
        if (EPI == 0) {
          ((u16*)Cv)[idx] = f2bf(v / (1.0f + expf(-v)));
        } else if (EPI == 1) {
          ((u16*)Cv)[idx] = f2bf(v * bf2f(gbuf[idx]));
        } else if (EPI == 2) {
          const float add = (choice[row] == 0) ? v : 0.0f;
          ((float*)Cv)[idx] = resf[idx] + add;
        } else {
          const float add = (choice[row] == 1) ? v : 0.0f;
          ((float*)Cv)[idx] += add;
        }
      }
    }
  }
}

// ---------------- launcher --------------------------------------------
extern "C" void kernel_launch(void* const* d_in, const int* in_sizes, int n_in,
                              void* d_out, int out_size, void* d_ws, size_t ws_size,
                              hipStream_t stream) {
  (void)in_sizes; (void)n_in; (void)out_size; (void)ws_size;
  const float* hidden = (const float*)d_in[0];
  const float* ln1w   = (const float*)d_in[1];
  const float* wq     = (const float*)d_in[2];
  const float* bq     = (const float*)d_in[3];
  const float* wk     = (const float*)d_in[4];
  const float* bk     = (const float*)d_in[5];
  const float* wv     = (const float*)d_in[6];
  const float* bv     = (const float*)d_in[7];
  const float* wo     = (const float*)d_in[8];
  const float* ln2w   = (const float*)d_in[9];
  const float* e1g    = (const float*)d_in[10];
  const float* e1u    = (const float*)d_in[11];
  const float* e1d    = (const float*)d_in[12];
  const float* e2g    = (const float*)d_in[13];
  const float* e2u    = (const float*)d_in[14];
  const float* e2d    = (const float*)d_in[15];
  const float* rw     = (const float*)d_in[16];
  const float* rb     = (const float*)d_in[17];
  float* out = (float*)d_out;
  char* ws = (char*)d_ws;

  const size_t MB = 1024 * 1024;
  // [0,32)   h1n (f32) -> ctx after QKV
  // [32,64)  Qb (f32)  -> res2 after attn
  // [64,96)  Kb (f32)  -> h2b (bf16, 16MB) after attn
  // [80,81)  (within dead Kb tail) chs
  // [96,141) Vb (f32, dead after attn) -> act bf16 45MB
  // [144,167) wbf bf16 22.5MB (per-matrix, reused 6x)
  float* h1n  = (float*)(ws);
  float* Qb   = (float*)(ws + 32 * MB);
  float* Kb   = (float*)(ws + 64 * MB);
  float* Vb   = (float*)(ws + 96 * MB);
  float* ctx  = h1n;
  float* res2 = Qb;
  u16*   h2b  = (u16*)(ws + 64 * MB);
  int*   chs  = (int*)(ws + 82 * MB);
  u16*   act  = (u16*)(ws + 96 * MB);
  u16*   wbf  = (u16*)(ws + 144 * MB);

  k_rmsnorm1<<<MTOK, 256, 0, stream>>>(hidden, ln1w, h1n);

  dim3 gQKV(D_ / 128, MTOK / 128);
  k_gemm_f32<0><<<gQKV, 256, 0, stream>>>(h1n, wq, bq, nullptr, Qb, D_, D_);
  k_gemm_f32<0><<<gQKV, 256, 0, stream>>>(h1n, wk, bk, nullptr, Kb, D_, D_);
  k_gemm_f32<0><<<gQKV, 256, 0, stream>>>(h1n, wv, bv, nullptr, Vb, D_, D_);

  k_rope<<<MTOK, 256, 0, stream>>>(Qb, Kb);
  k_attn<<<dim3(S_ / 64, NH_, 2), 256, 0, stream>>>(Qb, Kb, Vb, ctx);

  k_gemm_f32<1><<<gQKV, 256, 0, stream>>>(ctx, wo, nullptr, hidden, res2, D_, D_);

  k_rmsnorm2_router<<<MTOK, 256, 0, stream>>>(res2, ln2w, rw, rb, h2b, chs);

  const int WCONV = (F_ * D_) / 8 / 256;   // 5504 blocks per weight matrix
  dim3 gFU(F_ / 128, MTOK / 128), gDN(D_ / 128, MTOK / 128);

  // expert 1
  k_f2bf<<<WCONV, 256, 0, stream>>>(e1g, wbf);
  k_moe_bf16<0><<<gFU, 256, 0, stream>>>(h2b, wbf, nullptr, nullptr, nullptr, act, F_, D_);
  k_f2bf<<<WCONV, 256, 0, stream>>>(e1u, wbf);
  k_moe_bf16<1><<<gFU, 256, 0, stream>>>(h2b, wbf, act, nullptr, nullptr, act, F_, D_);
  k_f2bf<<<WCONV, 256, 0, stream>>>(e1d, wbf);
  k_moe_bf16<2><<<gDN, 256, 0, stream>>>(act, wbf, nullptr, res2, chs, out, D_, F_);
  // expert 2
  k_f2bf<<<WCONV, 256, 0, stream>>>(e2g, wbf);
  k_moe_bf16<0><<<gFU, 256, 0, stream>>>(h2b, wbf, nullptr, nullptr, nullptr, act, F_, D_);
  k_f2bf<<<WCONV, 256, 0, stream>>>(e2u, wbf);
  k_moe_bf16<1><<<gFU, 256, 0, stream>>>(h2b, wbf, act, nullptr, nullptr, act, F_, D_);
  k_f2bf<<<WCONV, 256, 0, stream>>>(e2d, wbf);
  k_moe_bf16<3><<<gDN, 256, 0, stream>>>(act, wbf, nullptr, res2, chs, out, D_, F_);
}